// Round 5
// baseline (130.289 us; speedup 1.0000x reference)
//
#include <hip/hip_runtime.h>
#include <math.h>

#define Bn 8
#define Qn 20
#define Pn 12
#define Nn 4096
#define Gn 2048
#define Mn 1280   /* Q*FACTOR */
#define Fn 64
#define KNB 7     /* K_NEIGHBORS - 1 */
#define NCOST 160
#define NREP 40
#define NBLK 616  /* 160 cost + 40 rep + 160 chamA (40x4) + 256 chamB (64x4) */
#define C2_TARGET 616
#define SCOPE_AGENT __HIP_MEMORY_SCOPE_AGENT

// ---------------- workspace layout (32-bit words) ----------------
// cham  : 0      (1920)   ns: 1920  dd: 3840  cost: 5760  cnt: 7680
// acc   : 7776   (6)      0 cls, 1 param, 2 pvd, 3 rep, 4 ch1, 5 ch2
// done  : 7782   cost-block counter (poison-baseline relative)
// base  : 7783   NEVER WRITTEN -> holds the fill poison pattern
// c2    : 7784   completion counter  (all 616 blocks)
// zflag : 7785   acc-zeroed flag (block0, release)
// repc  : 7786   rep sub-counter (40)
// rep   : 7808   (160) per-group repulsion partials
// chunkA: 8040   (40)  per-chunk sibling counters, chamfer A
// chunkB: 8080   (64)  per-chunk sibling counters, chamfer B
// pmA1  : 8192   pmA2: 90112  pmB1: 172032  pmB2: 253952 (partial min slots)
//
// R11: single dispatch, NO global gate (R10's 48us kernel = 20% VALUBusy:
// two-phase spin on an 840-bump counter serialized the tail at ~4% occupancy).
// Now: chamfer = 4 inner-split siblings per outer chunk; the 4th bumper of a
// per-chunk counter combines (fmin exact) + runs the bitwise-exact R9 tree +
// atomicAdd. Only 8 JV blocks spin, on a 160-bump cost counter. Rep reduced
// by the last of 40 rep blocks. acc zero gated by release/acquire zflag.
// Last of 616 c2 bumpers assembles out. All cross-block floats via uncached
// agent-scope ops (R10-proven); all reduction trees/values bitwise == R9.

__device__ __forceinline__ float aread(float* p) { return atomicAdd(p, 0.0f); }
__device__ __forceinline__ void ast(float* p, float v) {
    __hip_atomic_store(p, v, __ATOMIC_RELAXED, SCOPE_AGENT);
}
__device__ __forceinline__ float ald(const float* p) {
    return __hip_atomic_load(p, __ATOMIC_RELAXED, SCOPE_AGENT);
}

__device__ __forceinline__ int rdlane_i(int v, int l) {
    return __builtin_amdgcn_readlane(v, l);
}
__device__ __forceinline__ float rdlane_f(float v, int l) {
    return __int_as_float(__builtin_amdgcn_readlane(__float_as_int(v), l));
}
// full-wave min via DPP (VALU pipe); result valid in lane 63.
__device__ __forceinline__ unsigned wave_min_u32(unsigned x) {
    unsigned t;
    t = (unsigned)__builtin_amdgcn_update_dpp((int)0xFFFFFFFF, (int)x, 0x111, 0xF, 0xF, false);
    x = t < x ? t : x;
    t = (unsigned)__builtin_amdgcn_update_dpp((int)0xFFFFFFFF, (int)x, 0x112, 0xF, 0xF, false);
    x = t < x ? t : x;
    t = (unsigned)__builtin_amdgcn_update_dpp((int)0xFFFFFFFF, (int)x, 0x114, 0xF, 0xF, false);
    x = t < x ? t : x;
    t = (unsigned)__builtin_amdgcn_update_dpp((int)0xFFFFFFFF, (int)x, 0x118, 0xF, 0xF, false);
    x = t < x ? t : x;
    t = (unsigned)__builtin_amdgcn_update_dpp((int)0xFFFFFFFF, (int)x, 0x142, 0xF, 0xF, false);
    x = t < x ? t : x;
    t = (unsigned)__builtin_amdgcn_update_dpp((int)0xFFFFFFFF, (int)x, 0x143, 0xF, 0xF, false);
    x = t < x ? t : x;
    return x;
}

__device__ __forceinline__ void wait_zero(float* ws, unsigned init) {
    unsigned* z = (unsigned*)(ws + 7785);
    while (__hip_atomic_load(z, __ATOMIC_ACQUIRE, SCOPE_AGENT) - init != 1u)
        __builtin_amdgcn_s_sleep(1);
}

__device__ __forceinline__ void bump_c2(float* ws, float* out, unsigned init) {
    unsigned* c2P = (unsigned*)(ws + 7784);
    unsigned old = __hip_atomic_fetch_add(c2P, 1u, __ATOMIC_ACQ_REL, SCOPE_AGENT);
    if (old - init == (unsigned)(C2_TARGET - 1)) {
        float* acc = ws + 7776;
        float a0 = aread(&acc[0]);
        float a1 = aread(&acc[1]);
        float a2 = aread(&acc[2]);
        float a3 = aread(&acc[3]);
        float a4 = aread(&acc[4]);
        float a5 = aread(&acc[5]);
        out[0] = a0 + 0.5f * a1 + 20.f * a2 + a3 + a4 + a5;
        // restore all counters to poison baseline (harmless if re-poisoned)
        unsigned* w = (unsigned*)ws;
        __hip_atomic_store(&w[7782], init, __ATOMIC_RELAXED, SCOPE_AGENT);
        __hip_atomic_store(&w[7784], init, __ATOMIC_RELAXED, SCOPE_AGENT);
        __hip_atomic_store(&w[7785], init, __ATOMIC_RELAXED, SCOPE_AGENT);
        __hip_atomic_store(&w[7786], init, __ATOMIC_RELAXED, SCOPE_AGENT);
        for (int k = 0; k < 40; ++k)
            __hip_atomic_store(&w[8040 + k], init, __ATOMIC_RELAXED, SCOPE_AGENT);
        for (int k = 0; k < 64; ++k)
            __hip_atomic_store(&w[8080 + k], init, __ATOMIC_RELAXED, SCOPE_AGENT);
    }
}

__global__ void fused_kernel(const float* __restrict__ pred_logits,
                             const float* __restrict__ pred_normals,
                             const float* __restrict__ pred_distances,
                             const float* __restrict__ gt_normals,
                             const float* __restrict__ gt_distances,
                             const float* __restrict__ points,
                             const int*   __restrict__ gt_masks,
                             const float* __restrict__ recon,
                             const float* __restrict__ gt,
                             float* __restrict__ ws,
                             float* __restrict__ out) {
    __shared__ __align__(16) float smem[2 * Pn * 256];
    __shared__ int sflag;
    const int blk = blockIdx.x;
    const int tid = threadIdx.x;

    float* cham = ws;
    float* ns   = ws + 1920;
    float* dd   = ws + 3840;
    float* cost = ws + 5760;
    float* cnt  = ws + 7680;
    float* acc  = ws + 7776;
    unsigned* doneP = (unsigned*)(ws + 7782);
    unsigned* baseP = (unsigned*)(ws + 7783);
    unsigned* repcP = (unsigned*)(ws + 7786);
    unsigned* chunkA = (unsigned*)(ws + 8040);
    unsigned* chunkB = (unsigned*)(ws + 8080);
    float* rep_part = ws + 7808;
    float* pmA1 = ws + 8192;
    float* pmA2 = ws + 90112;
    float* pmB1 = ws + 172032;
    float* pmB2 = ws + 253952;

    const unsigned init = __hip_atomic_load(baseP, __ATOMIC_RELAXED, SCOPE_AGENT);

    if (blk < NCOST) {
        // ================= cost path (R10-verbatim) =================
        if (blk == 0 && tid < 6) ast(&acc[tid], 0.f);
        const int b = blk / Qn, q = blk % Qn;
        const float nx = pred_normals[(b * Qn + q) * 3 + 0];
        const float ny = pred_normals[(b * Qn + q) * 3 + 1];
        const float nz = pred_normals[(b * Qn + q) * 3 + 2];
        const float dq = pred_distances[b * Qn + q];

        float accs[Pn], accw[Pn];
#pragma unroll
        for (int p = 0; p < Pn; ++p) { accs[p] = 0.f; accw[p] = 0.f; }

        const float* ptb = points + (size_t)b * Nn * 3;
        const int*   mb  = gt_masks + (size_t)b * Pn * Nn;

        for (int n = tid; n < Nn; n += 256) {
            float px = ptb[n * 3 + 0], py = ptb[n * 3 + 1], pz = ptb[n * 3 + 2];
            float pp = fabsf(px * nx + py * ny + pz * nz - dq);
#pragma unroll
            for (int p = 0; p < Pn; ++p) {
                float m = (float)mb[(size_t)p * Nn + n];
                accs[p] += pp * m;
                accw[p] += m;
            }
        }
#pragma unroll
        for (int p = 0; p < Pn; ++p) {
            smem[p * 256 + tid] = accs[p];
            smem[(p + Pn) * 256 + tid] = accw[p];
        }
        __syncthreads();
        for (int off = 128; off > 0; off >>= 1) {
            if (tid < off) {
#pragma unroll
                for (int r = 0; r < 2 * Pn; ++r) smem[r * 256 + tid] += smem[r * 256 + tid + off];
            }
            __syncthreads();
        }
        if (tid < Pn) {
            const int p = tid;
            float c  = smem[(p + Pn) * 256];
            float cv = smem[p * 256] / fmaxf(c, 1.f);
            float gnx = gt_normals[(b * Pn + p) * 3 + 0];
            float gny = gt_normals[(b * Pn + p) * 3 + 1];
            float gnz = gt_normals[(b * Pn + p) * 3 + 2];
            float nsim = 1.f - fabsf(nx * gnx + ny * gny + nz * gnz);
            float ddv  = fabsf(dq - gt_distances[b * Pn + p]);
            int idx = (b * Qn + q) * Pn + p;
            ast(&cham[idx], cv);
            ast(&ns[idx],   nsim);
            ast(&dd[idx],   ddv);
            ast(&cost[idx], nsim + 0.5f * ddv + 5.f * ((c > 0.f) ? cv : 1.f));
            if (q == 0) ast(&cnt[b * Pn + p], c);
        }
        __syncthreads();   // drains all lanes' stores before publish
        if (tid == 0) {
            if (blk == 0) {
                unsigned* z = (unsigned*)(ws + 7785);
                __hip_atomic_store(z, init + 1u, __ATOMIC_RELEASE, SCOPE_AGENT);
            }
            __hip_atomic_fetch_add(doneP, 1u, __ATOMIC_RELEASE, SCOPE_AGENT);
        }

        if (blk >= 8) {
            if (tid == 0) bump_c2(ws, out, init);
            return;
        }

        // ---- JV blocks: tiny spin on the 160-bump cost counter ----
        if (tid == 0) {
            while (__hip_atomic_load(doneP, __ATOMIC_RELAXED, SCOPE_AGENT) - init != (unsigned)NCOST)
                __builtin_amdgcn_s_sleep(2);
            (void)__hip_atomic_load(doneP, __ATOMIC_ACQUIRE, SCOPE_AGENT);
        }
        __syncthreads();

        if (tid < 64) {
            const int b2 = blk;
            const int t = tid;
            const int col = t;
            const bool isCol = (col >= 1 && col <= Qn);

            float cr[Pn];
#pragma unroll
            for (int k = 0; k < Pn; ++k) cr[k] = 0.f;
            if (isCol) {
                const float* cb = cost + ((size_t)b2 * Qn + (col - 1)) * Pn;
#pragma unroll
                for (int k = 0; k < Pn; ++k) cr[k] = ald(&cb[k]);
            }

            float v = 0.f, u = 0.f, minv = 0.f;
            int way = 0, p = 0;

            for (int i = 1; i <= Pn; ++i) {
                minv = 1e30f;
                bool used = false;
                bool rowInPath = false;
                int j0s = 0;
                while (true) {
                    if (col == j0s) used = true;
                    int i0s = (j0s == 0) ? i : rdlane_i(p, j0s);
                    if (t == i0s) rowInPath = true;
                    float u_i0 = rdlane_f(u, i0s);
                    const int bs = i0s - 1;
                    float l10 = (bs & 1) ? cr[1]  : cr[0];
                    float l11 = (bs & 1) ? cr[3]  : cr[2];
                    float l12 = (bs & 1) ? cr[5]  : cr[4];
                    float l13 = (bs & 1) ? cr[7]  : cr[6];
                    float l14 = (bs & 1) ? cr[9]  : cr[8];
                    float l15 = (bs & 1) ? cr[11] : cr[10];
                    float l20 = (bs & 2) ? l11 : l10;
                    float l21 = (bs & 2) ? l13 : l12;
                    float l22 = (bs & 2) ? l15 : l14;
                    float cij = (bs >= 8) ? l22 : ((bs >= 4) ? l21 : l20);
                    if (isCol && !used) {
                        float cur = cij - u_i0 - v;
                        if (cur < minv) { minv = cur; way = j0s; }
                    }
                    float mv = (isCol && !used) ? minv : 1e30f;
                    unsigned kb = __float_as_uint(mv);
                    kb = ((int)kb < 0) ? ~kb : (kb | 0x80000000u);
                    kb = (kb & ~31u) | (unsigned)(col & 31);
                    unsigned kmin = (unsigned)rdlane_i((int)wave_min_u32(kb), 63);
                    int j1 = (int)(kmin & 31u);
                    float delta = rdlane_f(minv, j1);
                    if (used || col == 0) v -= delta;
                    else if (isCol)       minv -= delta;
                    if (rowInPath)        u += delta;
                    j0s = j1;
                    int pj0 = rdlane_i(p, j0s);
                    if (pj0 == 0) break;
                }
                while (j0s != 0) {
                    int wj = rdlane_i(way, j0s);
                    int pw = (wj == 0) ? i : rdlane_i(p, wj);
                    if (col == j0s) p = pw;
                    j0s = wj;
                }
            }

            float cls = 0.f, par = 0.f, pvd = 0.f;
            if (isCol) {
                float x = pred_logits[b2 * Qn + (col - 1)];
                float tgt = (p > 0) ? 1.f : 0.f;
                cls = fmaxf(x, 0.f) - x * tgt + log1pf(expf(-fabsf(x)));
                if (p > 0) {
                    int idx = (b2 * Qn + (col - 1)) * Pn + (p - 1);
                    par = ald(&ns[idx]) + ald(&dd[idx]);
                    pvd = (ald(&cnt[b2 * Pn + (p - 1)]) > 0.f) ? ald(&cham[idx]) : 0.f;
                }
            }
            for (int off = 32; off > 0; off >>= 1) {
                cls += __shfl_down(cls, off);
                par += __shfl_down(par, off);
                pvd += __shfl_down(pvd, off);
            }
            if (t == 0) {
                atomicAdd(&acc[0], cls / (float)(Bn * Qn));
                atomicAdd(&acc[1], par / (float)(Bn * Pn));
                atomicAdd(&acc[2], pvd / (float)(Bn * Pn));
                bump_c2(ws, out, init);
            }
        }
        return;
    } else if (blk < 200) {
        // ================= repulsion (R10-verbatim) + last-block reduce =================
        const int wave = tid >> 6, lane = tid & 63;
        const int g = (blk - NCOST) * 4 + wave;
        float* xs = smem + wave * 192;
        float* ys = xs + 64;
        float* zs = xs + 128;
        const float* base = recon + (size_t)g * Fn * 3;
        xs[lane] = base[lane * 3 + 0];
        ys[lane] = base[lane * 3 + 1];
        zs[lane] = base[lane * 3 + 2];
        float best[KNB];
#pragma unroll
        for (int k = 0; k < KNB; ++k) best[k] = 3.4e38f;
        const float xi = xs[lane], yi = ys[lane], zi = zs[lane];
        for (int j = 0; j < Fn; ++j) {
            float dx = xi - xs[j], dy = yi - ys[j], dz = zi - zs[j];
            float d2 = dx * dx + dy * dy + dz * dz;
            d2 = (j == lane) ? 3.4e38f : d2;
#pragma unroll
            for (int k = 0; k < KNB; ++k) {
                float lo = fminf(best[k], d2);
                float hi = fmaxf(best[k], d2);
                best[k] = lo;
                d2 = hi;
            }
        }
        float sum = 0.f;
#pragma unroll
        for (int k = 0; k < KNB; ++k) {
            float dn = fmaxf(best[k], 1e-12f);
            float w  = expf(-dn / (0.03f * 0.03f));
            sum += (0.07f - sqrtf(dn)) * w;
        }
        for (int off = 32; off > 0; off >>= 1) sum += __shfl_down(sum, off);
        if (lane == 0) ast(&rep_part[g], fmaxf(sum / (float)(Fn * KNB), 0.f));
        __syncthreads();   // drain stores
        if (tid == 0) {
            unsigned old = __hip_atomic_fetch_add(repcP, 1u, __ATOMIC_ACQ_REL, SCOPE_AGENT);
            sflag = (old - init == (unsigned)(NREP - 1)) ? 1 : 0;
        }
        __syncthreads();
        if (sflag) {
            // exact R9 rep reduce tree
            float* s1 = smem + 768;
            float c1 = (tid < Bn * Qn) ? ald(&rep_part[tid]) / (float)(Bn * Qn) : 0.f;
            s1[tid] = c1;
            __syncthreads();
            for (int off = 128; off > 0; off >>= 1) {
                if (tid < off) s1[tid] += s1[tid + off];
                __syncthreads();
            }
            if (tid == 0) {
                wait_zero(ws, init);
                atomicAdd(&acc[3], s1[0]);
            }
        }
        if (tid == 0) bump_c2(ws, out, init);
        return;
    }

    // ================= chamfer: 4 inner-split siblings per outer chunk =================
    float4* tile = reinterpret_cast<float4*>(smem);
    float* o1;
    float* o2;
    unsigned* ctr;
    int idx, chunk, s, nslots;
    float scale;
    float m1 = 3.4e38f, m2 = 3.4e38f;

    if (blk < 360) {
        // ---- A: outer = recon (B*M=10240), inner = gt[b] split 4x512 ----
        int a = blk - 200;
        chunk = a >> 2; s = a & 3;
        idx = chunk * 256 + tid;
        const int b = chunk / 5;                 // 1280 = 5*256
        const float* ip = gt + ((size_t)b * Gn + s * 512) * 3;
        {
            float4 tv;
            int j0 = tid;
            tv.x = ip[j0 * 3 + 0]; tv.y = ip[j0 * 3 + 1]; tv.z = ip[j0 * 3 + 2]; tv.w = 0.f;
            tile[j0] = tv;
            int j1 = tid + 256;
            tv.x = ip[j1 * 3 + 0]; tv.y = ip[j1 * 3 + 1]; tv.z = ip[j1 * 3 + 2]; tv.w = 0.f;
            tile[j1] = tv;
        }
        __syncthreads();
        const float x = recon[idx * 3 + 0], y = recon[idx * 3 + 1], z = recon[idx * 3 + 2];
#pragma unroll 4
        for (int j = 0; j < 512; ++j) {
            float4 tv = tile[j];
            float dx = x - tv.x, dy = y - tv.y, dz = z - tv.z;
            float d1 = fabsf(dx) + fabsf(dy) + fabsf(dz);
            float d2 = dx * dx + dy * dy + dz * dz;
            m1 = fminf(m1, d1); m2 = fminf(m2, d2);
        }
        o1 = pmA1; o2 = pmA2; ctr = &chunkA[chunk];
        nslots = Bn * Mn; scale = 0.5f / (float)(Bn * Mn);
    } else {
        // ---- B: outer = gt (B*G=16384), inner = recon[b] split 4x320 ----
        int a = blk - 360;
        chunk = a >> 2; s = a & 3;
        idx = chunk * 256 + tid;
        const int b = chunk / 8;                 // 2048 = 8*256
        const float* ip = recon + ((size_t)b * Mn + s * 320) * 3;
        {
            float4 tv;
            int j0 = tid;
            if (j0 < 320) {
                tv.x = ip[j0 * 3 + 0]; tv.y = ip[j0 * 3 + 1]; tv.z = ip[j0 * 3 + 2]; tv.w = 0.f;
                tile[j0] = tv;
            }
            int j1 = tid + 256;
            if (j1 < 320) {
                tv.x = ip[j1 * 3 + 0]; tv.y = ip[j1 * 3 + 1]; tv.z = ip[j1 * 3 + 2]; tv.w = 0.f;
                tile[j1] = tv;
            }
        }
        __syncthreads();
        const float x = gt[idx * 3 + 0], y = gt[idx * 3 + 1], z = gt[idx * 3 + 2];
#pragma unroll 4
        for (int j = 0; j < 320; ++j) {
            float4 tv = tile[j];
            float dx = x - tv.x, dy = y - tv.y, dz = z - tv.z;
            float d1 = fabsf(dx) + fabsf(dy) + fabsf(dz);
            float d2 = dx * dx + dy * dy + dz * dz;
            m1 = fminf(m1, d1); m2 = fminf(m2, d2);
        }
        o1 = pmB1; o2 = pmB2; ctr = &chunkB[chunk];
        nslots = Bn * Gn; scale = 0.5f / (float)(Bn * Gn);
    }

    ast(&o1[s * nslots + idx], m1);
    ast(&o2[s * nslots + idx], m2);
    __syncthreads();   // drain partial stores before publish
    if (tid == 0) {
        unsigned old = __hip_atomic_fetch_add(ctr, 1u, __ATOMIC_ACQ_REL, SCOPE_AGENT);
        sflag = (old - init == 3u) ? 1 : 0;
    }
    __syncthreads();
    if (sflag) {
        // last sibling combines (min exact) + exact R9 tree + atomicAdd
        float m1c = 3.4e38f, m2c = 3.4e38f;
#pragma unroll
        for (int ss = 0; ss < 4; ++ss) {
            m1c = fminf(m1c, ald(&o1[ss * nslots + idx]));
            m2c = fminf(m2c, ald(&o2[ss * nslots + idx]));
        }
        float* s1 = smem;
        float* s2 = smem + 256;
        s1[tid] = m1c * scale;
        s2[tid] = m2c * scale;
        __syncthreads();
        for (int off = 128; off > 0; off >>= 1) {
            if (tid < off) { s1[tid] += s1[tid + off]; s2[tid] += s2[tid + off]; }
            __syncthreads();
        }
        if (tid == 0) {
            wait_zero(ws, init);
            atomicAdd(&acc[4], s1[0]);
            atomicAdd(&acc[5], s2[0]);
        }
    }
    if (tid == 0) bump_c2(ws, out, init);
}

extern "C" void kernel_launch(void* const* d_in, const int* in_sizes, int n_in,
                              void* d_out, int out_size, void* d_ws, size_t ws_size,
                              hipStream_t stream) {
    const float* pred_logits    = (const float*)d_in[0];
    const float* pred_normals   = (const float*)d_in[1];
    const float* pred_distances = (const float*)d_in[2];
    const float* gt_normals     = (const float*)d_in[3];
    const float* gt_distances   = (const float*)d_in[4];
    const int*   gt_masks       = (const int*)d_in[5];
    const float* points         = (const float*)d_in[6];
    const float* recon          = (const float*)d_in[7];
    const float* gt             = (const float*)d_in[8];
    // d_in[9] (gt_index) is unused by the reference.

    fused_kernel<<<NBLK, 256, 0, stream>>>(pred_logits, pred_normals, pred_distances,
                                           gt_normals, gt_distances, points, gt_masks,
                                           recon, gt, (float*)d_ws, (float*)d_out);
}

// Round 6
// 114.056 us; speedup vs baseline: 1.1423x; 1.1423x over previous
//
#include <hip/hip_runtime.h>
#include <math.h>

#define Bn 8
#define Qn 20
#define Pn 12
#define Nn 4096
#define Gn 2048
#define Mn 1280   /* Q*FACTOR */
#define Fn 64
#define KNB 7     /* K_NEIGHBORS - 1 */
#define NCOST 160
#define NREP 20   /* 8 groups per block */
#define NCHA 40   /* chamfer A blocks: outer recon chunks of 256 */
#define NCHB 64   /* chamfer B blocks: outer gt chunks of 256 */
#define NBLK 284  /* 160 + 20 + 40 + 64 */
#define C2_TARGET 113 /* 8 JV + 1 rep-last + 104 chamfer */
#define SCOPE_AGENT __HIP_MEMORY_SCOPE_AGENT

// ---------------- workspace layout (32-bit words) ----------------
// cham  : 0      (1920)   ns: 1920  dd: 3840  cost: 5760  cnt: 7680
// acc   : 7776   (6)      0 cls, 1 param, 2 pvd, 3 rep, 4 ch1, 5 ch2
// base  : 7783   NEVER WRITTEN -> holds the fill poison pattern
// c2    : 7784   completion counter (113 contributors)
// zflag : 7785   acc-zeroed flag (block0, release)
// repc  : 7786   rep sub-counter (20)
// doneB : 7788   (8) per-batch cost counters (20 each) gating JV
// rep   : 7808   (160) per-group repulsion partials
//
// R12: single dispatch, ZERO cross-block bulk data. R11 post-mortem: the
// +25us came from 2.6MB of UNCACHED pm transport + hundreds of far RMWs,
// not the gate topology. Fix: chamfer inner-split moves INSIDE the block
// (512 threads: t and t+256 share outer point idx, take inner halves; whole
// inner cloud staged in LDS; halves fmin-combined via LDS -> bitwise == R9's
// 8-split min since min is order-exact; then R9's exact scale+tree+atomicAdd).
// pm arrays / chunk counters / reduce blocks deleted. Remaining uncached
// traffic: 7.7K-word cost group (R10-proven) + ~300 RMWs. JV gated per-batch
// (doneB[b]==20) so it starts as early as possible. All 284 blocks (4/CU,
// 32KB LDS, 512 thr) co-resident -> spins deadlock-free.

__device__ __forceinline__ float aread(float* p) { return atomicAdd(p, 0.0f); }
__device__ __forceinline__ void ast(float* p, float v) {
    __hip_atomic_store(p, v, __ATOMIC_RELAXED, SCOPE_AGENT);
}
__device__ __forceinline__ float ald(const float* p) {
    return __hip_atomic_load(p, __ATOMIC_RELAXED, SCOPE_AGENT);
}

__device__ __forceinline__ int rdlane_i(int v, int l) {
    return __builtin_amdgcn_readlane(v, l);
}
__device__ __forceinline__ float rdlane_f(float v, int l) {
    return __int_as_float(__builtin_amdgcn_readlane(__float_as_int(v), l));
}
// full-wave min via DPP (VALU pipe); result valid in lane 63.
__device__ __forceinline__ unsigned wave_min_u32(unsigned x) {
    unsigned t;
    t = (unsigned)__builtin_amdgcn_update_dpp((int)0xFFFFFFFF, (int)x, 0x111, 0xF, 0xF, false);
    x = t < x ? t : x;
    t = (unsigned)__builtin_amdgcn_update_dpp((int)0xFFFFFFFF, (int)x, 0x112, 0xF, 0xF, false);
    x = t < x ? t : x;
    t = (unsigned)__builtin_amdgcn_update_dpp((int)0xFFFFFFFF, (int)x, 0x114, 0xF, 0xF, false);
    x = t < x ? t : x;
    t = (unsigned)__builtin_amdgcn_update_dpp((int)0xFFFFFFFF, (int)x, 0x118, 0xF, 0xF, false);
    x = t < x ? t : x;
    t = (unsigned)__builtin_amdgcn_update_dpp((int)0xFFFFFFFF, (int)x, 0x142, 0xF, 0xF, false);
    x = t < x ? t : x;
    t = (unsigned)__builtin_amdgcn_update_dpp((int)0xFFFFFFFF, (int)x, 0x143, 0xF, 0xF, false);
    x = t < x ? t : x;
    return x;
}

__device__ __forceinline__ void wait_zero(float* ws, unsigned init) {
    unsigned* z = (unsigned*)(ws + 7785);
    while (__hip_atomic_load(z, __ATOMIC_ACQUIRE, SCOPE_AGENT) - init != 1u)
        __builtin_amdgcn_s_sleep(1);
}

__device__ __forceinline__ void bump_c2(float* ws, float* out, unsigned init) {
    unsigned* c2P = (unsigned*)(ws + 7784);
    unsigned old = __hip_atomic_fetch_add(c2P, 1u, __ATOMIC_ACQ_REL, SCOPE_AGENT);
    if (old - init == (unsigned)(C2_TARGET - 1)) {
        float* acc = ws + 7776;
        float a0 = aread(&acc[0]);
        float a1 = aread(&acc[1]);
        float a2 = aread(&acc[2]);
        float a3 = aread(&acc[3]);
        float a4 = aread(&acc[4]);
        float a5 = aread(&acc[5]);
        out[0] = a0 + 0.5f * a1 + 20.f * a2 + a3 + a4 + a5;
        // restore counters to poison baseline (harmless if re-poisoned)
        unsigned* w = (unsigned*)ws;
        __hip_atomic_store(&w[7784], init, __ATOMIC_RELAXED, SCOPE_AGENT);
        __hip_atomic_store(&w[7785], init, __ATOMIC_RELAXED, SCOPE_AGENT);
        __hip_atomic_store(&w[7786], init, __ATOMIC_RELAXED, SCOPE_AGENT);
        for (int k = 0; k < 8; ++k)
            __hip_atomic_store(&w[7788 + k], init, __ATOMIC_RELAXED, SCOPE_AGENT);
    }
}

__global__ __launch_bounds__(512, 2)
void fused_kernel(const float* __restrict__ pred_logits,
                  const float* __restrict__ pred_normals,
                  const float* __restrict__ pred_distances,
                  const float* __restrict__ gt_normals,
                  const float* __restrict__ gt_distances,
                  const float* __restrict__ points,
                  const int*   __restrict__ gt_masks,
                  const float* __restrict__ recon,
                  const float* __restrict__ gt,
                  float* __restrict__ ws,
                  float* __restrict__ out) {
    __shared__ __align__(16) float smem[8192];   // 32 KB
    __shared__ int sflag;
    const int blk = blockIdx.x;
    const int tid = threadIdx.x;

    float* cham = ws;
    float* ns   = ws + 1920;
    float* dd   = ws + 3840;
    float* cost = ws + 5760;
    float* cnt  = ws + 7680;
    float* acc  = ws + 7776;
    unsigned* baseP = (unsigned*)(ws + 7783);
    unsigned* repcP = (unsigned*)(ws + 7786);
    unsigned* doneB = (unsigned*)(ws + 7788);
    float* rep_part = ws + 7808;

    const unsigned init = __hip_atomic_load(baseP, __ATOMIC_RELAXED, SCOPE_AGENT);

    if (blk < NCOST) {
        // ================= cost path (R9 bitwise; tid<256 work, 512 at barriers) ======
        if (blk == 0 && tid < 6) ast(&acc[tid], 0.f);
        const int b = blk / Qn, q = blk % Qn;
        const float nx = pred_normals[(b * Qn + q) * 3 + 0];
        const float ny = pred_normals[(b * Qn + q) * 3 + 1];
        const float nz = pred_normals[(b * Qn + q) * 3 + 2];
        const float dq = pred_distances[b * Qn + q];

        if (tid < 256) {
            float accs[Pn], accw[Pn];
#pragma unroll
            for (int p = 0; p < Pn; ++p) { accs[p] = 0.f; accw[p] = 0.f; }
            const float* ptb = points + (size_t)b * Nn * 3;
            const int*   mb  = gt_masks + (size_t)b * Pn * Nn;
            for (int n = tid; n < Nn; n += 256) {
                float px = ptb[n * 3 + 0], py = ptb[n * 3 + 1], pz = ptb[n * 3 + 2];
                float pp = fabsf(px * nx + py * ny + pz * nz - dq);
#pragma unroll
                for (int p = 0; p < Pn; ++p) {
                    float m = (float)mb[(size_t)p * Nn + n];
                    accs[p] += pp * m;
                    accw[p] += m;
                }
            }
#pragma unroll
            for (int p = 0; p < Pn; ++p) {
                smem[p * 256 + tid] = accs[p];
                smem[(p + Pn) * 256 + tid] = accw[p];
            }
        }
        __syncthreads();
        for (int off = 128; off > 0; off >>= 1) {
            if (tid < off) {
#pragma unroll
                for (int r = 0; r < 2 * Pn; ++r) smem[r * 256 + tid] += smem[r * 256 + tid + off];
            }
            __syncthreads();
        }
        if (tid < Pn) {
            const int p = tid;
            float c  = smem[(p + Pn) * 256];
            float cv = smem[p * 256] / fmaxf(c, 1.f);
            float gnx = gt_normals[(b * Pn + p) * 3 + 0];
            float gny = gt_normals[(b * Pn + p) * 3 + 1];
            float gnz = gt_normals[(b * Pn + p) * 3 + 2];
            float nsim = 1.f - fabsf(nx * gnx + ny * gny + nz * gnz);
            float ddv  = fabsf(dq - gt_distances[b * Pn + p]);
            int idx = (b * Qn + q) * Pn + p;
            ast(&cham[idx], cv);
            ast(&ns[idx],   nsim);
            ast(&dd[idx],   ddv);
            ast(&cost[idx], nsim + 0.5f * ddv + 5.f * ((c > 0.f) ? cv : 1.f));
            if (q == 0) ast(&cnt[b * Pn + p], c);
        }
        __syncthreads();   // each wave drains its stores before tid0 publishes
        if (tid == 0) {
            if (blk == 0) {
                unsigned* z = (unsigned*)(ws + 7785);
                __hip_atomic_store(z, init + 1u, __ATOMIC_RELEASE, SCOPE_AGENT);
            }
            __hip_atomic_fetch_add(&doneB[b], 1u, __ATOMIC_RELEASE, SCOPE_AGENT);
        }
        if (blk >= 8) return;

        // ---- JV block b=blk: spin on its batch's 20 cost blocks ----
        if (tid == 0) {
            while (__hip_atomic_load(&doneB[blk], __ATOMIC_RELAXED, SCOPE_AGENT) - init != 20u)
                __builtin_amdgcn_s_sleep(2);
            (void)__hip_atomic_load(&doneB[blk], __ATOMIC_ACQUIRE, SCOPE_AGENT);
        }
        __syncthreads();

        if (tid < 64) {
            const int b2 = blk;
            const int t = tid;
            const int col = t;
            const bool isCol = (col >= 1 && col <= Qn);

            float cr[Pn];
#pragma unroll
            for (int k = 0; k < Pn; ++k) cr[k] = 0.f;
            if (isCol) {
                const float* cb = cost + ((size_t)b2 * Qn + (col - 1)) * Pn;
#pragma unroll
                for (int k = 0; k < Pn; ++k) cr[k] = ald(&cb[k]);
            }

            float v = 0.f, u = 0.f, minv = 0.f;
            int way = 0, p = 0;

            for (int i = 1; i <= Pn; ++i) {
                minv = 1e30f;
                bool used = false;
                bool rowInPath = false;
                int j0s = 0;
                while (true) {
                    if (col == j0s) used = true;
                    int i0s = (j0s == 0) ? i : rdlane_i(p, j0s);
                    if (t == i0s) rowInPath = true;
                    float u_i0 = rdlane_f(u, i0s);
                    const int bs = i0s - 1;
                    float l10 = (bs & 1) ? cr[1]  : cr[0];
                    float l11 = (bs & 1) ? cr[3]  : cr[2];
                    float l12 = (bs & 1) ? cr[5]  : cr[4];
                    float l13 = (bs & 1) ? cr[7]  : cr[6];
                    float l14 = (bs & 1) ? cr[9]  : cr[8];
                    float l15 = (bs & 1) ? cr[11] : cr[10];
                    float l20 = (bs & 2) ? l11 : l10;
                    float l21 = (bs & 2) ? l13 : l12;
                    float l22 = (bs & 2) ? l15 : l14;
                    float cij = (bs >= 8) ? l22 : ((bs >= 4) ? l21 : l20);
                    if (isCol && !used) {
                        float cur = cij - u_i0 - v;
                        if (cur < minv) { minv = cur; way = j0s; }
                    }
                    float mv = (isCol && !used) ? minv : 1e30f;
                    unsigned kb = __float_as_uint(mv);
                    kb = ((int)kb < 0) ? ~kb : (kb | 0x80000000u);
                    kb = (kb & ~31u) | (unsigned)(col & 31);
                    unsigned kmin = (unsigned)rdlane_i((int)wave_min_u32(kb), 63);
                    int j1 = (int)(kmin & 31u);
                    float delta = rdlane_f(minv, j1);
                    if (used || col == 0) v -= delta;
                    else if (isCol)       minv -= delta;
                    if (rowInPath)        u += delta;
                    j0s = j1;
                    int pj0 = rdlane_i(p, j0s);
                    if (pj0 == 0) break;
                }
                while (j0s != 0) {
                    int wj = rdlane_i(way, j0s);
                    int pw = (wj == 0) ? i : rdlane_i(p, wj);
                    if (col == j0s) p = pw;
                    j0s = wj;
                }
            }

            float cls = 0.f, par = 0.f, pvd = 0.f;
            if (isCol) {
                float x = pred_logits[b2 * Qn + (col - 1)];
                float tgt = (p > 0) ? 1.f : 0.f;
                cls = fmaxf(x, 0.f) - x * tgt + log1pf(expf(-fabsf(x)));
                if (p > 0) {
                    int idx = (b2 * Qn + (col - 1)) * Pn + (p - 1);
                    par = ald(&ns[idx]) + ald(&dd[idx]);
                    pvd = (ald(&cnt[b2 * Pn + (p - 1)]) > 0.f) ? ald(&cham[idx]) : 0.f;
                }
            }
            for (int off = 32; off > 0; off >>= 1) {
                cls += __shfl_down(cls, off);
                par += __shfl_down(par, off);
                pvd += __shfl_down(pvd, off);
            }
            if (t == 0) {
                wait_zero(ws, init);
                atomicAdd(&acc[0], cls / (float)(Bn * Qn));
                atomicAdd(&acc[1], par / (float)(Bn * Pn));
                atomicAdd(&acc[2], pvd / (float)(Bn * Pn));
                bump_c2(ws, out, init);
            }
        }
        return;
    } else if (blk < NCOST + NREP) {
        // ================= repulsion: 8 waves/block, 20 blocks =================
        const int wave = tid >> 6, lane = tid & 63;
        const int g = (blk - NCOST) * 8 + wave;
        float* xs = smem + wave * 192;
        float* ys = xs + 64;
        float* zs = xs + 128;
        const float* base = recon + (size_t)g * Fn * 3;
        xs[lane] = base[lane * 3 + 0];
        ys[lane] = base[lane * 3 + 1];
        zs[lane] = base[lane * 3 + 2];
        float best[KNB];
#pragma unroll
        for (int k = 0; k < KNB; ++k) best[k] = 3.4e38f;
        const float xi = xs[lane], yi = ys[lane], zi = zs[lane];
        for (int j = 0; j < Fn; ++j) {
            float dx = xi - xs[j], dy = yi - ys[j], dz = zi - zs[j];
            float d2 = dx * dx + dy * dy + dz * dz;
            d2 = (j == lane) ? 3.4e38f : d2;
#pragma unroll
            for (int k = 0; k < KNB; ++k) {
                float lo = fminf(best[k], d2);
                float hi = fmaxf(best[k], d2);
                best[k] = lo;
                d2 = hi;
            }
        }
        float sum = 0.f;
#pragma unroll
        for (int k = 0; k < KNB; ++k) {
            float dn = fmaxf(best[k], 1e-12f);
            float w  = expf(-dn / (0.03f * 0.03f));
            sum += (0.07f - sqrtf(dn)) * w;
        }
        for (int off = 32; off > 0; off >>= 1) sum += __shfl_down(sum, off);
        if (lane == 0) ast(&rep_part[g], fmaxf(sum / (float)(Fn * KNB), 0.f));
        __syncthreads();   // drain stores
        if (tid == 0) {
            unsigned old = __hip_atomic_fetch_add(repcP, 1u, __ATOMIC_ACQ_REL, SCOPE_AGENT);
            sflag = (old - init == (unsigned)(NREP - 1)) ? 1 : 0;
        }
        __syncthreads();
        if (sflag) {
            // exact R9 rep reduce tree (tid<256 active; all 512 at barriers)
            float* s1 = smem + 2048;
            if (tid < 256)
                s1[tid] = (tid < Bn * Qn) ? ald(&rep_part[tid]) / (float)(Bn * Qn) : 0.f;
            __syncthreads();
            for (int off = 128; off > 0; off >>= 1) {
                if (tid < off) s1[tid] += s1[tid + off];
                __syncthreads();
            }
            if (tid == 0) {
                wait_zero(ws, init);
                atomicAdd(&acc[3], s1[0]);
                bump_c2(ws, out, init);
            }
        }
        return;
    }

    // ================= chamfer: whole inner cloud in LDS, intra-block 2-way split ====
    {
        const int a = blk - (NCOST + NREP);
        const bool isA = (a < NCHA);
        const int chunk = isA ? a : (a - NCHA);
        const int lt = tid & 255;
        const int half = tid >> 8;           // 0 or 1
        const int idx = chunk * 256 + lt;    // outer point index (flat over B*pts)
        const float* inner;
        const float* op;
        int ninner;
        float scale;
        if (isA) {
            const int b = idx / Mn;          // outer = recon, inner = gt[b] (2048)
            inner = gt + (size_t)b * Gn * 3;
            op = recon + (size_t)idx * 3;
            ninner = Gn;
            scale = 0.5f / (float)(Bn * Mn);
        } else {
            const int b = idx / Gn;          // outer = gt, inner = recon[b] (1280)
            inner = recon + (size_t)b * Mn * 3;
            op = gt + (size_t)idx * 3;
            ninner = Mn;
            scale = 0.5f / (float)(Bn * Gn);
        }
        float4* tile = reinterpret_cast<float4*>(smem);
        for (int j = tid; j < ninner; j += 512) {
            const float* ip = inner + j * 3;
            float4 tv;
            tv.x = ip[0]; tv.y = ip[1]; tv.z = ip[2]; tv.w = 0.f;
            tile[j] = tv;
        }
        __syncthreads();
        const float x = op[0], y = op[1], z = op[2];
        const int j0 = half * (ninner >> 1), j1 = j0 + (ninner >> 1);
        float m1 = 3.4e38f, m2 = 3.4e38f;
#pragma unroll 4
        for (int j = j0; j < j1; ++j) {
            float4 tv = tile[j];
            float dx = x - tv.x, dy = y - tv.y, dz = z - tv.z;
            float d1 = fabsf(dx) + fabsf(dy) + fabsf(dz);
            float d2 = dx * dx + dy * dy + dz * dz;
            m1 = fminf(m1, d1); m2 = fminf(m2, d2);
        }
        __syncthreads();                     // tile dead; reuse smem
        float* s1 = smem;                    // [0,512)
        float* s2 = smem + 512;              // [512,1024)
        s1[tid] = m1;
        s2[tid] = m2;
        __syncthreads();
        float* t1 = smem + 1024;             // [1024,1280)
        float* t2 = smem + 1280;             // [1280,1536)
        if (tid < 256) {
            float M1 = fminf(s1[tid], s1[tid + 256]);   // min: order-exact
            float M2 = fminf(s2[tid], s2[tid + 256]);
            t1[tid] = M1 * scale;                        // == R9 reduce inputs, bitwise
            t2[tid] = M2 * scale;
        }
        __syncthreads();
        for (int off = 128; off > 0; off >>= 1) {
            if (tid < off) { t1[tid] += t1[tid + off]; t2[tid] += t2[tid + off]; }
            __syncthreads();
        }
        if (tid == 0) {
            wait_zero(ws, init);
            atomicAdd(&acc[4], t1[0]);
            atomicAdd(&acc[5], t2[0]);
            bump_c2(ws, out, init);
        }
    }
}

extern "C" void kernel_launch(void* const* d_in, const int* in_sizes, int n_in,
                              void* d_out, int out_size, void* d_ws, size_t ws_size,
                              hipStream_t stream) {
    const float* pred_logits    = (const float*)d_in[0];
    const float* pred_normals   = (const float*)d_in[1];
    const float* pred_distances = (const float*)d_in[2];
    const float* gt_normals     = (const float*)d_in[3];
    const float* gt_distances   = (const float*)d_in[4];
    const int*   gt_masks       = (const int*)d_in[5];
    const float* points         = (const float*)d_in[6];
    const float* recon          = (const float*)d_in[7];
    const float* gt             = (const float*)d_in[8];
    // d_in[9] (gt_index) is unused by the reference.

    fused_kernel<<<NBLK, 512, 0, stream>>>(pred_logits, pred_normals, pred_distances,
                                           gt_normals, gt_distances, points, gt_masks,
                                           recon, gt, (float*)d_ws, (float*)d_out);
}

// Round 7
// 110.013 us; speedup vs baseline: 1.1843x; 1.0367x over previous
//
#include <hip/hip_runtime.h>
#include <math.h>

#define Bn 8
#define Qn 20
#define Pn 12
#define Nn 4096
#define Gn 2048
#define Mn 1280   /* Q*FACTOR */
#define Fn 64
#define KNB 7     /* K_NEIGHBORS - 1 */
#define NCOST 160
#define NCHA 40   /* chamfer A blocks: outer recon chunks of 256 */
#define NCHB 64   /* chamfer B blocks: outer gt chunks of 256 */
#define NREP 20   /* 8 groups per block */
#define NBLK 284  /* 160 + 40 + 64 + 20 */
#define C2_TARGET 113 /* 8 JV + 104 chamfer + 1 rep-last */
#define SCOPE_AGENT __HIP_MEMORY_SCOPE_AGENT

// ---------------- workspace layout (32-bit words) ----------------
// cham  : 0      (1920)   ns: 1920  dd: 3840  cost: 5760  cnt: 7680
// base  : 7783   NEVER WRITTEN -> holds the fill poison pattern
// doneB : 7808+16b (b<8)  per-batch cost counters, EACH ON ITS OWN LINE
// c2    : 7936   completion counter (own line)
// repslt: 7952   rep result slot (own line)
// repc  : 7968   rep sub-counter (own line)
// jvslot: 8000+16b (b<8)  {cls,par,pvd} per batch, own line each
// slotA : 8192+16c (c<40) {c1,c2} per A chunk, own line each
// slotB : 8896+16c (c<64) {c1,c2} per B chunk, own line each
// rep   : 10240  (160) per-group repulsion partials
//
// R13: R12 minus the single-line RMW storm. R12 counters showed WRITE 927K->
// 62K (bulk fixed) but 51us @ 21% VALUBusy: ~500 device-scope RMWs + acquire
// spins all hit ONE 64B line (acc/c2/zflag/repc/doneB co-resident). Now every
// contributor stores partials to a PRIVATE line (relaxed uncached store) and
// does ONE release-RMW on a dedicated c2 line; the 113th bumper sums slots in
// fixed order and writes out. acc/zflag/wait_zero deleted. doneB spread to 8
// lines. XCD swizzle: cost blk = q*8+b (batch data lands in ONE XCD's L2,
// FETCH was 8.8MB vs 2.3MB inputs); chamfer chunks likewise on XCD = batch.
// Inner numerics bitwise == R12.

__device__ __forceinline__ void ast(float* p, float v) {
    __hip_atomic_store(p, v, __ATOMIC_RELAXED, SCOPE_AGENT);
}
__device__ __forceinline__ float ald(const float* p) {
    return __hip_atomic_load(p, __ATOMIC_RELAXED, SCOPE_AGENT);
}

__device__ __forceinline__ int rdlane_i(int v, int l) {
    return __builtin_amdgcn_readlane(v, l);
}
__device__ __forceinline__ float rdlane_f(float v, int l) {
    return __int_as_float(__builtin_amdgcn_readlane(__float_as_int(v), l));
}
// full-wave min via DPP (VALU pipe); result valid in lane 63.
__device__ __forceinline__ unsigned wave_min_u32(unsigned x) {
    unsigned t;
    t = (unsigned)__builtin_amdgcn_update_dpp((int)0xFFFFFFFF, (int)x, 0x111, 0xF, 0xF, false);
    x = t < x ? t : x;
    t = (unsigned)__builtin_amdgcn_update_dpp((int)0xFFFFFFFF, (int)x, 0x112, 0xF, 0xF, false);
    x = t < x ? t : x;
    t = (unsigned)__builtin_amdgcn_update_dpp((int)0xFFFFFFFF, (int)x, 0x114, 0xF, 0xF, false);
    x = t < x ? t : x;
    t = (unsigned)__builtin_amdgcn_update_dpp((int)0xFFFFFFFF, (int)x, 0x118, 0xF, 0xF, false);
    x = t < x ? t : x;
    t = (unsigned)__builtin_amdgcn_update_dpp((int)0xFFFFFFFF, (int)x, 0x142, 0xF, 0xF, false);
    x = t < x ? t : x;
    t = (unsigned)__builtin_amdgcn_update_dpp((int)0xFFFFFFFF, (int)x, 0x143, 0xF, 0xF, false);
    x = t < x ? t : x;
    return x;
}

// one release-RMW per contributor; the 113th sums all slots (fixed order).
__device__ __forceinline__ void bump_c2(float* ws, float* out, unsigned init) {
    unsigned* c2P = (unsigned*)(ws + 7936);
    unsigned old = __hip_atomic_fetch_add(c2P, 1u, __ATOMIC_ACQ_REL, SCOPE_AGENT);
    if (old - init == (unsigned)(C2_TARGET - 1)) {
        float a0 = 0.f, a1 = 0.f, a2 = 0.f, a4 = 0.f, a5 = 0.f;
#pragma unroll
        for (int b = 0; b < 8; ++b) {
            a0 += ald(ws + 8000 + 16 * b + 0);
            a1 += ald(ws + 8000 + 16 * b + 1);
            a2 += ald(ws + 8000 + 16 * b + 2);
        }
#pragma unroll
        for (int c = 0; c < NCHA; ++c) {
            a4 += ald(ws + 8192 + 16 * c + 0);
            a5 += ald(ws + 8192 + 16 * c + 1);
        }
#pragma unroll
        for (int c = 0; c < NCHB; ++c) {
            a4 += ald(ws + 8896 + 16 * c + 0);
            a5 += ald(ws + 8896 + 16 * c + 1);
        }
        float a3 = ald(ws + 7952);
        out[0] = a0 + 0.5f * a1 + 20.f * a2 + a3 + a4 + a5;
        // restore counters to poison baseline (harmless if re-poisoned)
        unsigned* w = (unsigned*)ws;
        __hip_atomic_store(&w[7936], init, __ATOMIC_RELAXED, SCOPE_AGENT);
        __hip_atomic_store(&w[7968], init, __ATOMIC_RELAXED, SCOPE_AGENT);
#pragma unroll
        for (int b = 0; b < 8; ++b)
            __hip_atomic_store(&w[7808 + 16 * b], init, __ATOMIC_RELAXED, SCOPE_AGENT);
    }
}

__global__ __launch_bounds__(512, 2)
void fused_kernel(const float* __restrict__ pred_logits,
                  const float* __restrict__ pred_normals,
                  const float* __restrict__ pred_distances,
                  const float* __restrict__ gt_normals,
                  const float* __restrict__ gt_distances,
                  const float* __restrict__ points,
                  const int*   __restrict__ gt_masks,
                  const float* __restrict__ recon,
                  const float* __restrict__ gt,
                  float* __restrict__ ws,
                  float* __restrict__ out) {
    __shared__ __align__(16) float smem[8192];   // 32 KB
    __shared__ int sflag;
    const int blk = blockIdx.x;
    const int tid = threadIdx.x;

    float* cham = ws;
    float* ns   = ws + 1920;
    float* dd   = ws + 3840;
    float* cost = ws + 5760;
    float* cnt  = ws + 7680;
    unsigned* baseP = (unsigned*)(ws + 7783);
    unsigned* repcP = (unsigned*)(ws + 7968);
    float* rep_part = ws + 10240;

    const unsigned init = __hip_atomic_load(baseP, __ATOMIC_RELAXED, SCOPE_AGENT);

    if (blk < NCOST) {
        // ================= cost path (bitwise == R12; XCD-swizzled mapping) =========
        const int b = blk & 7, q = blk >> 3;   // blk%8 = batch -> one XCD's L2
        const float nx = pred_normals[(b * Qn + q) * 3 + 0];
        const float ny = pred_normals[(b * Qn + q) * 3 + 1];
        const float nz = pred_normals[(b * Qn + q) * 3 + 2];
        const float dq = pred_distances[b * Qn + q];

        if (tid < 256) {
            float accs[Pn], accw[Pn];
#pragma unroll
            for (int p = 0; p < Pn; ++p) { accs[p] = 0.f; accw[p] = 0.f; }
            const float* ptb = points + (size_t)b * Nn * 3;
            const int*   mb  = gt_masks + (size_t)b * Pn * Nn;
            for (int n = tid; n < Nn; n += 256) {
                float px = ptb[n * 3 + 0], py = ptb[n * 3 + 1], pz = ptb[n * 3 + 2];
                float pp = fabsf(px * nx + py * ny + pz * nz - dq);
#pragma unroll
                for (int p = 0; p < Pn; ++p) {
                    float m = (float)mb[(size_t)p * Nn + n];
                    accs[p] += pp * m;
                    accw[p] += m;
                }
            }
#pragma unroll
            for (int p = 0; p < Pn; ++p) {
                smem[p * 256 + tid] = accs[p];
                smem[(p + Pn) * 256 + tid] = accw[p];
            }
        }
        __syncthreads();
        for (int off = 128; off > 0; off >>= 1) {
            if (tid < off) {
#pragma unroll
                for (int r = 0; r < 2 * Pn; ++r) smem[r * 256 + tid] += smem[r * 256 + tid + off];
            }
            __syncthreads();
        }
        if (tid < Pn) {
            const int p = tid;
            float c  = smem[(p + Pn) * 256];
            float cv = smem[p * 256] / fmaxf(c, 1.f);
            float gnx = gt_normals[(b * Pn + p) * 3 + 0];
            float gny = gt_normals[(b * Pn + p) * 3 + 1];
            float gnz = gt_normals[(b * Pn + p) * 3 + 2];
            float nsim = 1.f - fabsf(nx * gnx + ny * gny + nz * gnz);
            float ddv  = fabsf(dq - gt_distances[b * Pn + p]);
            int idx = (b * Qn + q) * Pn + p;
            ast(&cham[idx], cv);
            ast(&ns[idx],   nsim);
            ast(&dd[idx],   ddv);
            ast(&cost[idx], nsim + 0.5f * ddv + 5.f * ((c > 0.f) ? cv : 1.f));
            if (q == 0) ast(&cnt[b * Pn + p], c);
        }
        __syncthreads();   // each wave drains its stores before tid0 publishes
        if (tid == 0)
            __hip_atomic_fetch_add((unsigned*)(ws + 7808 + 16 * b), 1u,
                                   __ATOMIC_RELEASE, SCOPE_AGENT);
        if (blk >= 8) return;

        // ---- JV block: batch b == blk (q==0 swizzled block); spin on its 20 ----
        if (tid == 0) {
            unsigned* dB = (unsigned*)(ws + 7808 + 16 * blk);
            while (__hip_atomic_load(dB, __ATOMIC_RELAXED, SCOPE_AGENT) - init != 20u)
                __builtin_amdgcn_s_sleep(2);
            (void)__hip_atomic_load(dB, __ATOMIC_ACQUIRE, SCOPE_AGENT);
        }
        __syncthreads();

        if (tid < 64) {
            const int b2 = blk;
            const int t = tid;
            const int col = t;
            const bool isCol = (col >= 1 && col <= Qn);

            float cr[Pn];
#pragma unroll
            for (int k = 0; k < Pn; ++k) cr[k] = 0.f;
            if (isCol) {
                const float* cb = cost + ((size_t)b2 * Qn + (col - 1)) * Pn;
#pragma unroll
                for (int k = 0; k < Pn; ++k) cr[k] = ald(&cb[k]);
            }

            float v = 0.f, u = 0.f, minv = 0.f;
            int way = 0, p = 0;

            for (int i = 1; i <= Pn; ++i) {
                minv = 1e30f;
                bool used = false;
                bool rowInPath = false;
                int j0s = 0;
                while (true) {
                    if (col == j0s) used = true;
                    int i0s = (j0s == 0) ? i : rdlane_i(p, j0s);
                    if (t == i0s) rowInPath = true;
                    float u_i0 = rdlane_f(u, i0s);
                    const int bs = i0s - 1;
                    float l10 = (bs & 1) ? cr[1]  : cr[0];
                    float l11 = (bs & 1) ? cr[3]  : cr[2];
                    float l12 = (bs & 1) ? cr[5]  : cr[4];
                    float l13 = (bs & 1) ? cr[7]  : cr[6];
                    float l14 = (bs & 1) ? cr[9]  : cr[8];
                    float l15 = (bs & 1) ? cr[11] : cr[10];
                    float l20 = (bs & 2) ? l11 : l10;
                    float l21 = (bs & 2) ? l13 : l12;
                    float l22 = (bs & 2) ? l15 : l14;
                    float cij = (bs >= 8) ? l22 : ((bs >= 4) ? l21 : l20);
                    if (isCol && !used) {
                        float cur = cij - u_i0 - v;
                        if (cur < minv) { minv = cur; way = j0s; }
                    }
                    float mv = (isCol && !used) ? minv : 1e30f;
                    unsigned kb = __float_as_uint(mv);
                    kb = ((int)kb < 0) ? ~kb : (kb | 0x80000000u);
                    kb = (kb & ~31u) | (unsigned)(col & 31);
                    unsigned kmin = (unsigned)rdlane_i((int)wave_min_u32(kb), 63);
                    int j1 = (int)(kmin & 31u);
                    float delta = rdlane_f(minv, j1);
                    if (used || col == 0) v -= delta;
                    else if (isCol)       minv -= delta;
                    if (rowInPath)        u += delta;
                    j0s = j1;
                    int pj0 = rdlane_i(p, j0s);
                    if (pj0 == 0) break;
                }
                while (j0s != 0) {
                    int wj = rdlane_i(way, j0s);
                    int pw = (wj == 0) ? i : rdlane_i(p, wj);
                    if (col == j0s) p = pw;
                    j0s = wj;
                }
            }

            float cls = 0.f, par = 0.f, pvd = 0.f;
            if (isCol) {
                float x = pred_logits[b2 * Qn + (col - 1)];
                float tgt = (p > 0) ? 1.f : 0.f;
                cls = fmaxf(x, 0.f) - x * tgt + log1pf(expf(-fabsf(x)));
                if (p > 0) {
                    int idx = (b2 * Qn + (col - 1)) * Pn + (p - 1);
                    par = ald(&ns[idx]) + ald(&dd[idx]);
                    pvd = (ald(&cnt[b2 * Pn + (p - 1)]) > 0.f) ? ald(&cham[idx]) : 0.f;
                }
            }
            for (int off = 32; off > 0; off >>= 1) {
                cls += __shfl_down(cls, off);
                par += __shfl_down(par, off);
                pvd += __shfl_down(pvd, off);
            }
            if (t == 0) {
                float* slot = ws + 8000 + 16 * b2;   // private line
                ast(slot + 0, cls / (float)(Bn * Qn));
                ast(slot + 1, par / (float)(Bn * Pn));
                ast(slot + 2, pvd / (float)(Bn * Pn));
                bump_c2(ws, out, init);
            }
        }
        return;
    } else if (blk < NCOST + NCHA + NCHB) {
        // ============ chamfer: whole inner cloud in LDS, intra-block 2-way split =====
        const int a = blk - NCOST;
        const bool isA = (a < NCHA);
        // XCD swizzle: chunk placed so blk%8 == its batch
        int chunk;
        if (isA) { int r = a;         chunk = (r & 7) * 5 + (r >> 3); }
        else     { int r = a - NCHA;  chunk = (r & 7) * 8 + (r >> 3); }
        const int lt = tid & 255;
        const int half = tid >> 8;           // 0 or 1
        const int idx = chunk * 256 + lt;    // outer point index (flat over B*pts)
        const float* inner;
        const float* op;
        int ninner;
        float scale;
        float* slot;
        if (isA) {
            const int b = idx / Mn;          // outer = recon, inner = gt[b] (2048)
            inner = gt + (size_t)b * Gn * 3;
            op = recon + (size_t)idx * 3;
            ninner = Gn;
            scale = 0.5f / (float)(Bn * Mn);
            slot = ws + 8192 + 16 * chunk;
        } else {
            const int b = idx / Gn;          // outer = gt, inner = recon[b] (1280)
            inner = recon + (size_t)b * Mn * 3;
            op = gt + (size_t)idx * 3;
            ninner = Mn;
            scale = 0.5f / (float)(Bn * Gn);
            slot = ws + 8896 + 16 * chunk;
        }
        float4* tile = reinterpret_cast<float4*>(smem);
        for (int j = tid; j < ninner; j += 512) {
            const float* ip = inner + j * 3;
            float4 tv;
            tv.x = ip[0]; tv.y = ip[1]; tv.z = ip[2]; tv.w = 0.f;
            tile[j] = tv;
        }
        __syncthreads();
        const float x = op[0], y = op[1], z = op[2];
        const int j0 = half * (ninner >> 1), j1 = j0 + (ninner >> 1);
        float m1 = 3.4e38f, m2 = 3.4e38f;
#pragma unroll 4
        for (int j = j0; j < j1; ++j) {
            float4 tv = tile[j];
            float dx = x - tv.x, dy = y - tv.y, dz = z - tv.z;
            float d1 = fabsf(dx) + fabsf(dy) + fabsf(dz);
            float d2 = dx * dx + dy * dy + dz * dz;
            m1 = fminf(m1, d1); m2 = fminf(m2, d2);
        }
        __syncthreads();                     // tile dead; reuse smem
        float* s1 = smem;                    // [0,512)
        float* s2 = smem + 512;              // [512,1024)
        s1[tid] = m1;
        s2[tid] = m2;
        __syncthreads();
        float* t1 = smem + 1024;             // [1024,1280)
        float* t2 = smem + 1280;             // [1280,1536)
        if (tid < 256) {
            float M1 = fminf(s1[tid], s1[tid + 256]);   // min: order-exact
            float M2 = fminf(s2[tid], s2[tid + 256]);
            t1[tid] = M1 * scale;                        // == R9 reduce inputs, bitwise
            t2[tid] = M2 * scale;
        }
        __syncthreads();
        for (int off = 128; off > 0; off >>= 1) {
            if (tid < off) { t1[tid] += t1[tid + off]; t2[tid] += t2[tid + off]; }
            __syncthreads();
        }
        if (tid == 0) {
            ast(slot + 0, t1[0]);
            ast(slot + 1, t2[0]);
            bump_c2(ws, out, init);
        }
        return;
    }

    // ================= repulsion: 8 waves/block, 20 blocks =================
    {
        const int wave = tid >> 6, lane = tid & 63;
        const int g = (blk - (NCOST + NCHA + NCHB)) * 8 + wave;
        float* xs = smem + wave * 192;
        float* ys = xs + 64;
        float* zs = xs + 128;
        const float* base = recon + (size_t)g * Fn * 3;
        xs[lane] = base[lane * 3 + 0];
        ys[lane] = base[lane * 3 + 1];
        zs[lane] = base[lane * 3 + 2];
        float best[KNB];
#pragma unroll
        for (int k = 0; k < KNB; ++k) best[k] = 3.4e38f;
        const float xi = xs[lane], yi = ys[lane], zi = zs[lane];
        for (int j = 0; j < Fn; ++j) {
            float dx = xi - xs[j], dy = yi - ys[j], dz = zi - zs[j];
            float d2 = dx * dx + dy * dy + dz * dz;
            d2 = (j == lane) ? 3.4e38f : d2;
#pragma unroll
            for (int k = 0; k < KNB; ++k) {
                float lo = fminf(best[k], d2);
                float hi = fmaxf(best[k], d2);
                best[k] = lo;
                d2 = hi;
            }
        }
        float sum = 0.f;
#pragma unroll
        for (int k = 0; k < KNB; ++k) {
            float dn = fmaxf(best[k], 1e-12f);
            float w  = expf(-dn / (0.03f * 0.03f));
            sum += (0.07f - sqrtf(dn)) * w;
        }
        for (int off = 32; off > 0; off >>= 1) sum += __shfl_down(sum, off);
        if (lane == 0) ast(&rep_part[g], fmaxf(sum / (float)(Fn * KNB), 0.f));
        __syncthreads();   // drain stores
        if (tid == 0) {
            unsigned old = __hip_atomic_fetch_add(repcP, 1u, __ATOMIC_ACQ_REL, SCOPE_AGENT);
            sflag = (old - init == (unsigned)(NREP - 1)) ? 1 : 0;
        }
        __syncthreads();
        if (sflag) {
            // exact rep reduce tree (tid<256 active; all 512 at barriers)
            float* s1 = smem + 2048;
            if (tid < 256)
                s1[tid] = (tid < Bn * Qn) ? ald(&rep_part[tid]) / (float)(Bn * Qn) : 0.f;
            __syncthreads();
            for (int off = 128; off > 0; off >>= 1) {
                if (tid < off) s1[tid] += s1[tid + off];
                __syncthreads();
            }
            if (tid == 0) {
                ast(ws + 7952, s1[0]);
                bump_c2(ws, out, init);
            }
        }
    }
}

extern "C" void kernel_launch(void* const* d_in, const int* in_sizes, int n_in,
                              void* d_out, int out_size, void* d_ws, size_t ws_size,
                              hipStream_t stream) {
    const float* pred_logits    = (const float*)d_in[0];
    const float* pred_normals   = (const float*)d_in[1];
    const float* pred_distances = (const float*)d_in[2];
    const float* gt_normals     = (const float*)d_in[3];
    const float* gt_distances   = (const float*)d_in[4];
    const int*   gt_masks       = (const int*)d_in[5];
    const float* points         = (const float*)d_in[6];
    const float* recon          = (const float*)d_in[7];
    const float* gt             = (const float*)d_in[8];
    // d_in[9] (gt_index) is unused by the reference.

    fused_kernel<<<NBLK, 512, 0, stream>>>(pred_logits, pred_normals, pred_distances,
                                           gt_normals, gt_distances, points, gt_masks,
                                           recon, gt, (float*)d_ws, (float*)d_out);
}